// Round 14
// baseline (102.497 us; speedup 1.0000x reference)
//
#include <hip/hip_runtime.h>
#include <hip/hip_bf16.h>

#define N_NODES 100000
#define DN      256
#define DE      128
#define DOUT    256
#define M1      32768
#define BSZ     8192
#define E1      327680
#define E2      81920
#define DIN     640
#define DAGG    384
#define WELEMS  (DOUT * DIN)

#define CDIV(a,b) (((a)+(b)-1)/(b))

// zero region: cnt1[M1] cnt2[BSZ] claim[M1] nn[64] zrow[256] — contiguous ints at ws base
#define ZERO_INTS (M1 + BSZ + M1 + 64 + 256)
#define S1_ZB 73            // CDIV(ZERO_INTS, 1024)
#define S1_CB 80            // 2*WELEMS / 4 / 1024
#define S2_MB 8             // BSZ / 1024 (dedup blocks)
#define S2_EB 400           // (E1+E2) / 1024 (edge blocks)
#define S2_NB 3125          // nf conversion: 25.6M elems / (1024*8)
#define GEMM1_BLOCKS 512    // 128 row-tiles x 4 col-tiles

typedef __attribute__((ext_vector_type(8))) short bf16x8;
typedef __attribute__((ext_vector_type(4))) float f32x4;
typedef __attribute__((ext_vector_type(2))) float f32x2;
typedef __attribute__((ext_vector_type(4))) unsigned short u16x4;
typedef __attribute__((ext_vector_type(2))) unsigned short u16x2;

__device__ __forceinline__ unsigned short f32_bf16(float f) {
  unsigned u = __float_as_uint(f);
  unsigned r = (u + 0x7FFF + ((u >> 16) & 1)) >> 16;
  return (unsigned short)r;
}

// ---- setup1: zero bookkeeping region + convert W1/W2 to bf16 --------------

__global__ __launch_bounds__(1024) void setup1_kernel(int* __restrict__ zbase,
                                                      const float* __restrict__ W1,
                                                      const float* __restrict__ W2,
                                                      unsigned short* __restrict__ Wb1,
                                                      unsigned short* __restrict__ Wb2) {
  int b = blockIdx.x, t = threadIdx.x;
  if (b < S1_ZB) {
    int i = b * 1024 + t;
    if (i < ZERO_INTS) zbase[i] = 0;
  } else {
    int i = ((b - S1_ZB) * 1024 + t) * 4;
    const float* s; unsigned short* d; int o;
    if (i < WELEMS) { s = W1; d = Wb1; o = i; }
    else { s = W2; d = Wb2; o = i - WELEMS; }
    f32x4 v = *reinterpret_cast<const f32x4*>(s + o);
    u16x4 r;
    r[0] = f32_bf16(v[0]); r[1] = f32_bf16(v[1]);
    r[2] = f32_bf16(v[2]); r[3] = f32_bf16(v[3]);
    *reinterpret_cast<u16x4*>(d + o) = r;
  }
}

// ---- setup2: CAS-dedup + bucket CSR build + nf->bf16 conversion -----------
// The three block ranges are independent; conversion (BW-bound) co-schedules
// with the atomic-heavy CSR build instead of costing a serial pass.

__global__ __launch_bounds__(1024) void setup2_kernel(const int* __restrict__ self2,
                                                      int* __restrict__ claim,
                                                      const int* __restrict__ self1,
                                                      int* __restrict__ remap,
                                                      int* __restrict__ needed,
                                                      int* __restrict__ selfrow1,
                                                      int* __restrict__ nn,
                                                      const int* __restrict__ seg1,
                                                      const int* __restrict__ from1,
                                                      int* __restrict__ cnt1,
                                                      int2* __restrict__ bkt1,
                                                      const int* __restrict__ seg2,
                                                      const int* __restrict__ from2,
                                                      int* __restrict__ cnt2,
                                                      int2* __restrict__ bkt2,
                                                      const float* __restrict__ nf,
                                                      unsigned short* __restrict__ nfb) {
  int b = blockIdx.x, t = threadIdx.x;
  if (b < S2_MB) {
    int m = self2[b * 1024 + t];
    if (atomicCAS(&claim[m], 0, 1) == 0) {
      int p = atomicAdd(nn, 1);
      remap[m] = p;
      needed[p] = m;
      selfrow1[p] = self1[m];
    }
  } else if (b < S2_MB + S2_EB) {
    int e = (b - S2_MB) * 1024 + t;
    if (e < E1) {
      int s = seg1[e];
      int p = atomicAdd(&cnt1[s], 1);
      if (p < 64) bkt1[s * 64 + p] = make_int2(from1[e], e);
    } else {
      int e2 = e - E1;
      int s = seg2[e2];
      int p = atomicAdd(&cnt2[s], 1);
      if (p < 64) bkt2[s * 64 + p] = make_int2(from2[e2], e2);
    }
  } else {
    // nf f32 -> bf16: 8 elems/thread, exact coverage (3125*8192 == 25.6M)
    int i = (b - S2_MB - S2_EB) * 8192 + t * 8;
    f32x4 v0 = *reinterpret_cast<const f32x4*>(nf + i);
    f32x4 v1 = *reinterpret_cast<const f32x4*>(nf + i + 4);
    bf16x8 r;
#pragma unroll
    for (int j = 0; j < 4; ++j) {
      r[j] = (short)f32_bf16(v0[j]);
      r[4 + j] = (short)f32_bf16(v1[j]);
    }
    *reinterpret_cast<bf16x8*>(nfb + i) = r;
  }
}

// ---- shared device body: aggregate 2 segments for one wave ----------------
// Lane l owns nfb cols [4l..4l+3] (u16x4, 8B) and ef cols [2l..2l+1] (f32x2).

__device__ __forceinline__ void agg_two_segments(int m0, bool v0, int m1, bool v1,
                                                 int r0, const int* __restrict__ cnt,
                                                 const int2* __restrict__ bkt,
                                                 const float* __restrict__ ef,
                                                 unsigned short* __restrict__ aggout,
                                                 const unsigned short* __restrict__ nfb,
                                                 const float* __restrict__ zrow,
                                                 int l) {
  int mm[2] = {m0, m1};
  bool vv[2] = {v0, v1};
  int base_[2], nc_[2];
#pragma unroll
  for (int s = 0; s < 2; ++s) {
    nc_[s] = vv[s] ? min(cnt[mm[s]], 64) : 0;
    base_[s] = mm[s] * 64;
  }
  int eidp[2], fidp[2];
#pragma unroll
  for (int s = 0; s < 2; ++s) {
    eidp[s] = 0; fidp[s] = 0;
    if (l < nc_[s]) {
      int2 d = bkt[base_[s] + l];
      fidp[s] = d.x; eidp[s] = d.y;
    }
  }
  const unsigned short* zna = (const unsigned short*)zrow + l * 4;  // 8B zeros
  const float* zrb = zrow + l * 2;

  f32x4 accn[2];
  f32x2 accf[2];
#pragma unroll
  for (int s = 0; s < 2; ++s) {
    accn[s] = (f32x4)0.f;
    accf[s] = (f32x2)0.f;
    int nc = nc_[s];
    int eid = eidp[s], fid = fidp[s];
    for (int j = 0; j < nc; j += 8) {
      u16x4 a[8]; f32x2 b[8];
#pragma unroll
      for (int q = 0; q < 8; ++q) {
        int jj = j + q;
        int fq = __shfl(fid, jj & 63);
        int gq = __shfl(eid, jj & 63);
        bool ok = jj < nc;
        const unsigned short* pa = ok ? (nfb + (size_t)fq * 256 + l * 4) : zna;
        const float* pb = ok ? (ef + (size_t)gq * 128 + l * 2) : zrb;
        a[q] = *reinterpret_cast<const u16x4*>(pa);
        b[q] = *reinterpret_cast<const f32x2*>(pb);
      }
#pragma unroll
      for (int q = 0; q < 8; ++q)
#pragma unroll
        for (int i = 0; i < 4; ++i)
          accn[s][i] += __uint_as_float(((unsigned)a[q][i]) << 16);
      accf[s] += ((b[0] + b[1]) + (b[2] + b[3])) + ((b[4] + b[5]) + (b[6] + b[7]));
    }
  }

#pragma unroll
  for (int s = 0; s < 2; ++s) {
    unsigned short* orow = aggout + (size_t)(r0 + s) * DAGG;
    u16x4 on;
    on[0] = f32_bf16(accn[s][0]); on[1] = f32_bf16(accn[s][1]);
    on[2] = f32_bf16(accn[s][2]); on[3] = f32_bf16(accn[s][3]);
    *reinterpret_cast<u16x4*>(orow + l * 4) = on;
    u16x2 oe;
    oe[0] = f32_bf16(accf[s][0]); oe[1] = f32_bf16(accf[s][1]);
    *reinterpret_cast<u16x2*>(orow + 256 + l * 2) = oe;
  }
}

// ---- agg1: layer-1 live segments only (critical path) ---------------------

__global__ __launch_bounds__(256) void agg1_kernel(const int* __restrict__ needed,
                                                   const int* __restrict__ nn_dev,
                                                   const int* __restrict__ cnt1,
                                                   const int2* __restrict__ bkt1,
                                                   const float* __restrict__ ef1,
                                                   unsigned short* __restrict__ agg1,
                                                   const unsigned short* __restrict__ nfb,
                                                   const float* __restrict__ zrow) {
  int wv = (blockIdx.x * 256 + threadIdx.x) >> 6;   // 0..4095
  int l = threadIdx.x & 63;
  int s0 = wv * 2;
  int nnv = *nn_dev;
  bool v0 = s0 < nnv, v1 = (s0 + 1) < nnv;
  if (!v0) return;
  int m0 = needed[s0];
  int m1 = v1 ? needed[s0 + 1] : 0;
  agg_two_segments(m0, v0, m1, v1, s0, cnt1, bkt1, ef1, agg1, nfb, zrow, l);
}

// ---- GEMM device body (R8 shape: BM=64, BN=64, BK=64, prefetch) -----------
// MODE 0 (layer1): row = i1[r];      out = bf16 h1.  table = nfb (bf16).
// MODE 1 (layer2): row = i2[i1[r]];  out = f32 final. table = h1 (bf16).

template<int MODE>
__device__ __forceinline__ void gemm_body(int bx, int by,
                                          const unsigned short* __restrict__ tabb,
                                          const int* __restrict__ i1,
                                          const int* __restrict__ i2,
                                          const unsigned short* __restrict__ agg,
                                          const unsigned short* __restrict__ Wb,
                                          float* __restrict__ outf,
                                          unsigned short* __restrict__ outb,
                                          int nrows) {
  const int row0 = bx * 64;
  if (row0 >= nrows) return;
  const int col0 = by * 64;

  __shared__ unsigned short As[64][72];
  __shared__ unsigned short Bs[64][72];

  const int t = threadIdx.x;
  const int lane = t & 63, wid = t >> 6;
  const int wm = wid >> 1, wn = wid & 1;

  const int srow = t >> 2;
  const int scol = (t & 3) * 16;
  const int grow = row0 + srow;
  int ga = -1;
  if (grow < nrows) { int x = i1[grow]; ga = (MODE == 1) ? i2[x] : x; }
  const unsigned short* wrow = Wb + (size_t)(col0 + srow) * DIN + scol;
  const unsigned short* tabrow = (ga >= 0) ? tabb + (size_t)ga * 256 : nullptr;
  const unsigned short* aggrow = agg + (size_t)grow * DAGG;

  f32x4 acc[2][2];
#pragma unroll
  for (int m = 0; m < 2; ++m)
#pragma unroll
    for (int n = 0; n < 2; ++n) acc[m][n] = (f32x4)0.f;

  bf16x8 ra0, ra1, rb0, rb1;

  auto loadA = [&](int k0, bf16x8& r0, bf16x8& r1) {
    int k = k0 + scol;
    if (ga < 0) { r0 = (bf16x8)(short)0; r1 = (bf16x8)(short)0; return; }
    if (k < 256) {
      r0 = *reinterpret_cast<const bf16x8*>(tabrow + k);
      r1 = *reinterpret_cast<const bf16x8*>(tabrow + k + 8);
    } else {
      r0 = *reinterpret_cast<const bf16x8*>(aggrow + (k - 256));
      r1 = *reinterpret_cast<const bf16x8*>(aggrow + (k - 256) + 8);
    }
  };

  loadA(0, ra0, ra1);
  rb0 = *reinterpret_cast<const bf16x8*>(wrow);
  rb1 = *reinterpret_cast<const bf16x8*>(wrow + 8);

  for (int k0 = 0; k0 < DIN; k0 += 64) {
    *reinterpret_cast<bf16x8*>(&As[srow][scol]) = ra0;
    *reinterpret_cast<bf16x8*>(&As[srow][scol + 8]) = ra1;
    *reinterpret_cast<bf16x8*>(&Bs[srow][scol]) = rb0;
    *reinterpret_cast<bf16x8*>(&Bs[srow][scol + 8]) = rb1;
    __syncthreads();

    if (k0 + 64 < DIN) {
      loadA(k0 + 64, ra0, ra1);
      rb0 = *reinterpret_cast<const bf16x8*>(wrow + k0 + 64);
      rb1 = *reinterpret_cast<const bf16x8*>(wrow + k0 + 64 + 8);
    }

#pragma unroll
    for (int ks = 0; ks < 2; ++ks) {
      bf16x8 af[2], bg[2];
#pragma unroll
      for (int m = 0; m < 2; ++m)
        af[m] = *reinterpret_cast<const bf16x8*>(
            &As[wm * 32 + m * 16 + (lane & 15)][ks * 32 + (lane >> 4) * 8]);
#pragma unroll
      for (int n = 0; n < 2; ++n)
        bg[n] = *reinterpret_cast<const bf16x8*>(
            &Bs[wn * 32 + n * 16 + (lane & 15)][ks * 32 + (lane >> 4) * 8]);
#pragma unroll
      for (int m = 0; m < 2; ++m)
#pragma unroll
        for (int n = 0; n < 2; ++n)
          acc[m][n] = __builtin_amdgcn_mfma_f32_16x16x32_bf16(af[m], bg[n], acc[m][n], 0, 0, 0);
    }
    __syncthreads();
  }

  const int rbase = row0 + wm * 32;
  const int cbase = col0 + wn * 32;
#pragma unroll
  for (int m = 0; m < 2; ++m)
#pragma unroll
    for (int n = 0; n < 2; ++n)
#pragma unroll
      for (int g = 0; g < 4; ++g) {
        int r = rbase + m * 16 + (lane >> 4) * 4 + g;
        if (r < nrows) {
          int c = cbase + n * 16 + (lane & 15);
          float x = fmaxf(acc[m][n][g], 0.f);
          if (MODE == 0) outb[(size_t)r * DOUT + c] = f32_bf16(x);
          else outf[(size_t)r * DOUT + c] = x;
        }
      }
}

// ---- L4: gemm1 (blocks 0..511) || agg2 (blocks 512..1535) -----------------

__global__ __launch_bounds__(256, 4) void gemm1_agg2_kernel(const unsigned short* __restrict__ nfb,
                                                            const int* __restrict__ selfrow1,
                                                            const unsigned short* __restrict__ agg1,
                                                            const unsigned short* __restrict__ Wb1,
                                                            unsigned short* __restrict__ h1c,
                                                            const int* __restrict__ nn_dev,
                                                            const int* __restrict__ cnt2,
                                                            const int2* __restrict__ bkt2,
                                                            const float* __restrict__ ef2,
                                                            unsigned short* __restrict__ agg2,
                                                            const float* __restrict__ zrow) {
  int b = blockIdx.x;
  if (b < GEMM1_BLOCKS) {
    gemm_body<0>(b >> 2, b & 3, nfb, selfrow1, nullptr, agg1, Wb1,
                 nullptr, h1c, *nn_dev);
  } else {
    int wv = ((b - GEMM1_BLOCKS) * 256 + threadIdx.x) >> 6;  // 0..4095
    int l = threadIdx.x & 63;
    int s0 = wv * 2;                                          // 0..8190
    agg_two_segments(s0, true, s0 + 1, true, s0, cnt2, bkt2, ef2, agg2,
                     nfb, zrow, l);
  }
}

// ---- gemm2 ----------------------------------------------------------------

__global__ __launch_bounds__(256, 4) void gemm2_kernel(const unsigned short* __restrict__ h1c,
                                                       const int* __restrict__ self2,
                                                       const int* __restrict__ remap,
                                                       const unsigned short* __restrict__ agg2,
                                                       const unsigned short* __restrict__ Wb2,
                                                       float* __restrict__ out) {
  gemm_body<1>(blockIdx.x, blockIdx.y, h1c, self2, remap, agg2, Wb2,
               out, nullptr, BSZ);
}

// ---- launcher ------------------------------------------------------------

extern "C" void kernel_launch(void* const* d_in, const int* in_sizes, int n_in,
                              void* d_out, int out_size, void* d_ws, size_t ws_size,
                              hipStream_t stream) {
  const float* nf   = (const float*)d_in[0];
  const float* ef1  = (const float*)d_in[1];
  const float* ef2  = (const float*)d_in[2];
  const float* W1   = (const float*)d_in[3];
  const float* W2   = (const float*)d_in[4];
  const int* from1  = (const int*)d_in[5];
  const int* seg1   = (const int*)d_in[6];
  const int* self1  = (const int*)d_in[7];
  const int* from2  = (const int*)d_in[8];
  const int* seg2   = (const int*)d_in[9];
  const int* self2  = (const int*)d_in[10];
  float* out = (float*)d_out;

  char* w = (char*)d_ws;
  size_t o = 0;
  auto take = [&](size_t nb) -> char* {
    char* p = w + o;
    o += (nb + 255) & ~(size_t)255;
    return p;
  };
  // zero region (cleared by setup1): cnt1, cnt2, claim, nn, zrow — ZERO_INTS ints
  int* cnt1 = (int*)take((size_t)M1 * 4);
  int* cnt2 = (int*)take((size_t)BSZ * 4);
  int* claim = (int*)take((size_t)M1 * 4);
  int* nn   = (int*)take(256);
  float* zrow = (float*)take((size_t)256 * 4);
  int* remap    = (int*)take((size_t)M1 * 4);
  int* needed   = (int*)take((size_t)8192 * 4);
  int* selfrow1 = (int*)take((size_t)8192 * 4);
  int2* bkt1    = (int2*)take((size_t)M1 * 64 * 8);
  int2* bkt2    = (int2*)take((size_t)BSZ * 64 * 8);
  unsigned short* Wb1   = (unsigned short*)take((size_t)WELEMS * 2);
  unsigned short* Wb2   = (unsigned short*)take((size_t)WELEMS * 2);
  unsigned short* nfb   = (unsigned short*)take((size_t)N_NODES * DN * 2);
  unsigned short* agg1c = (unsigned short*)take((size_t)8192 * DAGG * 2);
  unsigned short* agg2  = (unsigned short*)take((size_t)8192 * DAGG * 2);
  unsigned short* h1c   = (unsigned short*)take((size_t)8192 * DOUT * 2);

  setup1_kernel<<<S1_ZB + S1_CB, 1024, 0, stream>>>((int*)d_ws, W1, W2, Wb1, Wb2);
  setup2_kernel<<<S2_MB + S2_EB + S2_NB, 1024, 0, stream>>>(self2, claim, self1, remap,
                                                            needed, selfrow1, nn,
                                                            seg1, from1, cnt1, bkt1,
                                                            seg2, from2, cnt2, bkt2,
                                                            nf, nfb);
  agg1_kernel<<<1024, 256, 0, stream>>>(needed, nn, cnt1, bkt1, ef1, agg1c, nfb, zrow);
  gemm1_agg2_kernel<<<GEMM1_BLOCKS + 1024, 256, 0, stream>>>(nfb, selfrow1, agg1c, Wb1,
                                                             h1c, nn,
                                                             cnt2, bkt2, ef2, agg2, zrow);
  gemm2_kernel<<<dim3(128, 4), 256, 0, stream>>>(h1c, self2, remap, agg2, Wb2, out);
}

// Round 15
// 95.541 us; speedup vs baseline: 1.0728x; 1.0728x over previous
//
#include <hip/hip_runtime.h>
#include <hip/hip_bf16.h>

#define N_NODES 100000
#define DN      256
#define DE      128
#define DOUT    256
#define M1      32768
#define BSZ     8192
#define E1      327680
#define E2      81920
#define DIN     640
#define DAGG    384
#define WELEMS  (DOUT * DIN)

#define CDIV(a,b) (((a)+(b)-1)/(b))

// zero region: cnt1[M1] cnt2[BSZ] claim[M1] nn[64] zrow[256] — contiguous ints at ws base
#define ZERO_INTS (M1 + BSZ + M1 + 64 + 256)
#define S1_ZB 73            // CDIV(ZERO_INTS, 1024)
#define S2_MB 8             // BSZ / 1024 (dedup blocks)
#define S2_EB 400           // (E1+E2) / 1024 (edge blocks)
#define S2_WB 80            // W conversion: 2*WELEMS / 4 / 1024
#define AGG2_BLOCKS 1024    // 8192 layer-2 slots, 2 segs/wave
#define GEMM1_BLOCKS 512    // 128 row-tiles x 4 col-tiles

typedef __attribute__((ext_vector_type(8))) short bf16x8;
typedef __attribute__((ext_vector_type(4))) float f32x4;
typedef __attribute__((ext_vector_type(2))) float f32x2;
typedef __attribute__((ext_vector_type(4))) unsigned short u16x4;
typedef __attribute__((ext_vector_type(2))) unsigned short u16x2;

__device__ __forceinline__ unsigned short f32_bf16(float f) {
  unsigned u = __float_as_uint(f);
  unsigned r = (u + 0x7FFF + ((u >> 16) & 1)) >> 16;
  return (unsigned short)r;
}

// ---- setup1: zero bookkeeping region only (critical path, tiny) -----------

__global__ __launch_bounds__(1024) void setup1_kernel(int* __restrict__ zbase) {
  int i = blockIdx.x * 1024 + threadIdx.x;
  if (i < ZERO_INTS) zbase[i] = 0;
}

// ---- setup2: CAS-dedup + single-pass bucket CSR build + W->bf16 -----------
// Block ranges are independent; W conversion (BW-bound) co-schedules with the
// atomic-heavy CSR build.

__global__ __launch_bounds__(1024) void setup2_kernel(const int* __restrict__ self2,
                                                      int* __restrict__ claim,
                                                      const int* __restrict__ self1,
                                                      int* __restrict__ remap,
                                                      int* __restrict__ needed,
                                                      int* __restrict__ selfrow1,
                                                      int* __restrict__ nn,
                                                      const int* __restrict__ seg1,
                                                      const int* __restrict__ from1,
                                                      int* __restrict__ cnt1,
                                                      int2* __restrict__ bkt1,
                                                      const int* __restrict__ seg2,
                                                      const int* __restrict__ from2,
                                                      int* __restrict__ cnt2,
                                                      int2* __restrict__ bkt2,
                                                      const float* __restrict__ W1,
                                                      const float* __restrict__ W2,
                                                      unsigned short* __restrict__ Wb1,
                                                      unsigned short* __restrict__ Wb2) {
  int b = blockIdx.x, t = threadIdx.x;
  if (b < S2_MB) {
    int m = self2[b * 1024 + t];
    if (atomicCAS(&claim[m], 0, 1) == 0) {
      int p = atomicAdd(nn, 1);
      remap[m] = p;
      needed[p] = m;
      selfrow1[p] = self1[m];
    }
  } else if (b < S2_MB + S2_EB) {
    int e = (b - S2_MB) * 1024 + t;
    if (e < E1) {
      int s = seg1[e];
      int p = atomicAdd(&cnt1[s], 1);
      if (p < 64) bkt1[s * 64 + p] = make_int2(from1[e], e);
    } else {
      int e2 = e - E1;
      int s = seg2[e2];
      int p = atomicAdd(&cnt2[s], 1);
      if (p < 64) bkt2[s * 64 + p] = make_int2(from2[e2], e2);
    }
  } else {
    int i = ((b - S2_MB - S2_EB) * 1024 + t) * 4;
    const float* s; unsigned short* d; int o;
    if (i < WELEMS) { s = W1; d = Wb1; o = i; }
    else { s = W2; d = Wb2; o = i - WELEMS; }
    f32x4 v = *reinterpret_cast<const f32x4*>(s + o);
    u16x4 r;
    r[0] = f32_bf16(v[0]); r[1] = f32_bf16(v[1]);
    r[2] = f32_bf16(v[2]); r[3] = f32_bf16(v[3]);
    *reinterpret_cast<u16x4*>(d + o) = r;
  }
}

// ---- shared device body: aggregate 2 segments for one wave ----------------
// Lane l owns nf cols [4l..4l+3] (f32x4) and ef cols [2l..2l+1] (f32x2).

__device__ __forceinline__ void agg_two_segments(int m0, bool v0, int m1, bool v1,
                                                 int r0, const int* __restrict__ cnt,
                                                 const int2* __restrict__ bkt,
                                                 const float* __restrict__ ef,
                                                 unsigned short* __restrict__ aggout,
                                                 const float* __restrict__ nf,
                                                 const float* __restrict__ zrow,
                                                 int l) {
  int mm[2] = {m0, m1};
  bool vv[2] = {v0, v1};
  int base_[2], nc_[2];
#pragma unroll
  for (int s = 0; s < 2; ++s) {
    nc_[s] = vv[s] ? min(cnt[mm[s]], 64) : 0;
    base_[s] = mm[s] * 64;
  }
  int eidp[2], fidp[2];
#pragma unroll
  for (int s = 0; s < 2; ++s) {
    eidp[s] = 0; fidp[s] = 0;
    if (l < nc_[s]) {
      int2 d = bkt[base_[s] + l];
      fidp[s] = d.x; eidp[s] = d.y;
    }
  }
  const float* zra = zrow + l * 4;
  const float* zrb = zrow + l * 2;

  f32x4 accn[2];
  f32x2 accf[2];
#pragma unroll
  for (int s = 0; s < 2; ++s) {
    accn[s] = (f32x4)0.f;
    accf[s] = (f32x2)0.f;
    int nc = nc_[s];
    int eid = eidp[s], fid = fidp[s];
    for (int j = 0; j < nc; j += 8) {
      f32x4 a[8]; f32x2 b[8];
#pragma unroll
      for (int q = 0; q < 8; ++q) {
        int jj = j + q;
        int fq = __shfl(fid, jj & 63);
        int gq = __shfl(eid, jj & 63);
        bool ok = jj < nc;
        const float* pa = ok ? (nf + (size_t)fq * 256 + l * 4) : zra;
        const float* pb = ok ? (ef + (size_t)gq * 128 + l * 2) : zrb;
        a[q] = *reinterpret_cast<const f32x4*>(pa);
        b[q] = *reinterpret_cast<const f32x2*>(pb);
      }
      accn[s] += ((a[0] + a[1]) + (a[2] + a[3])) + ((a[4] + a[5]) + (a[6] + a[7]));
      accf[s] += ((b[0] + b[1]) + (b[2] + b[3])) + ((b[4] + b[5]) + (b[6] + b[7]));
    }
  }

#pragma unroll
  for (int s = 0; s < 2; ++s) {
    unsigned short* orow = aggout + (size_t)(r0 + s) * DAGG;
    u16x4 on;
    on[0] = f32_bf16(accn[s][0]); on[1] = f32_bf16(accn[s][1]);
    on[2] = f32_bf16(accn[s][2]); on[3] = f32_bf16(accn[s][3]);
    *reinterpret_cast<u16x4*>(orow + l * 4) = on;
    u16x2 oe;
    oe[0] = f32_bf16(accf[s][0]); oe[1] = f32_bf16(accf[s][1]);
    *reinterpret_cast<u16x2*>(orow + 256 + l * 2) = oe;
  }
}

// ---- agg1: layer-1 live segments only (critical path) ---------------------

__global__ __launch_bounds__(256) void agg1_kernel(const int* __restrict__ needed,
                                                   const int* __restrict__ nn_dev,
                                                   const int* __restrict__ cnt1,
                                                   const int2* __restrict__ bkt1,
                                                   const float* __restrict__ ef1,
                                                   unsigned short* __restrict__ agg1,
                                                   const float* __restrict__ nf,
                                                   const float* __restrict__ zrow) {
  int wv = (blockIdx.x * 256 + threadIdx.x) >> 6;   // 0..4095
  int l = threadIdx.x & 63;
  int s0 = wv * 2;
  int nnv = *nn_dev;
  bool v0 = s0 < nnv, v1 = (s0 + 1) < nnv;
  if (!v0) return;
  int m0 = needed[s0];
  int m1 = v1 ? needed[s0 + 1] : 0;
  agg_two_segments(m0, v0, m1, v1, s0, cnt1, bkt1, ef1, agg1, nf, zrow, l);
}

// ---- GEMM device body (R8 shape: BM=64, BN=64, BK=64, prefetch) -----------
// MODE 0 (layer1): table = nf (f32), row = i1[r];        out = bf16 h1
// MODE 1 (layer2): table = h1 (bf16), row = i2[i1[r]];   out = f32 final

template<int MODE>
__device__ __forceinline__ void gemm_body(int bx, int by,
                                          const float* __restrict__ tabf,
                                          const unsigned short* __restrict__ tabb,
                                          const int* __restrict__ i1,
                                          const int* __restrict__ i2,
                                          const unsigned short* __restrict__ agg,
                                          const unsigned short* __restrict__ Wb,
                                          float* __restrict__ outf,
                                          unsigned short* __restrict__ outb,
                                          int nrows) {
  const int row0 = bx * 64;
  if (row0 >= nrows) return;
  const int col0 = by * 64;

  __shared__ unsigned short As[64][72];
  __shared__ unsigned short Bs[64][72];

  const int t = threadIdx.x;
  const int lane = t & 63, wid = t >> 6;
  const int wm = wid >> 1, wn = wid & 1;

  const int srow = t >> 2;
  const int scol = (t & 3) * 16;
  const int grow = row0 + srow;
  int ga = -1;
  if (grow < nrows) { int x = i1[grow]; ga = (MODE == 1) ? i2[x] : x; }
  const unsigned short* wrow = Wb + (size_t)(col0 + srow) * DIN + scol;
  const float* tabrow_f = (MODE == 0 && ga >= 0) ? tabf + (size_t)ga * 256 : nullptr;
  const unsigned short* tabrow_b = (MODE == 1 && ga >= 0) ? tabb + (size_t)ga * 256 : nullptr;
  const unsigned short* aggrow = agg + (size_t)grow * DAGG;

  f32x4 acc[2][2];
#pragma unroll
  for (int m = 0; m < 2; ++m)
#pragma unroll
    for (int n = 0; n < 2; ++n) acc[m][n] = (f32x4)0.f;

  bf16x8 ra0, ra1, rb0, rb1;

  auto loadA = [&](int k0, bf16x8& r0, bf16x8& r1) {
    int k = k0 + scol;
    if (ga < 0) { r0 = (bf16x8)(short)0; r1 = (bf16x8)(short)0; return; }
    if (k < 256) {
      if (MODE == 0) {
        const float* s = tabrow_f + k;
        f32x4 x0 = *reinterpret_cast<const f32x4*>(s);
        f32x4 x1 = *reinterpret_cast<const f32x4*>(s + 4);
        f32x4 x2 = *reinterpret_cast<const f32x4*>(s + 8);
        f32x4 x3 = *reinterpret_cast<const f32x4*>(s + 12);
#pragma unroll
        for (int j = 0; j < 4; ++j) {
          r0[j] = (short)f32_bf16(x0[j]); r0[4 + j] = (short)f32_bf16(x1[j]);
          r1[j] = (short)f32_bf16(x2[j]); r1[4 + j] = (short)f32_bf16(x3[j]);
        }
      } else {
        r0 = *reinterpret_cast<const bf16x8*>(tabrow_b + k);
        r1 = *reinterpret_cast<const bf16x8*>(tabrow_b + k + 8);
      }
    } else {
      r0 = *reinterpret_cast<const bf16x8*>(aggrow + (k - 256));
      r1 = *reinterpret_cast<const bf16x8*>(aggrow + (k - 256) + 8);
    }
  };

  loadA(0, ra0, ra1);
  rb0 = *reinterpret_cast<const bf16x8*>(wrow);
  rb1 = *reinterpret_cast<const bf16x8*>(wrow + 8);

  for (int k0 = 0; k0 < DIN; k0 += 64) {
    *reinterpret_cast<bf16x8*>(&As[srow][scol]) = ra0;
    *reinterpret_cast<bf16x8*>(&As[srow][scol + 8]) = ra1;
    *reinterpret_cast<bf16x8*>(&Bs[srow][scol]) = rb0;
    *reinterpret_cast<bf16x8*>(&Bs[srow][scol + 8]) = rb1;
    __syncthreads();

    if (k0 + 64 < DIN) {
      loadA(k0 + 64, ra0, ra1);
      rb0 = *reinterpret_cast<const bf16x8*>(wrow + k0 + 64);
      rb1 = *reinterpret_cast<const bf16x8*>(wrow + k0 + 64 + 8);
    }

#pragma unroll
    for (int ks = 0; ks < 2; ++ks) {
      bf16x8 af[2], bg[2];
#pragma unroll
      for (int m = 0; m < 2; ++m)
        af[m] = *reinterpret_cast<const bf16x8*>(
            &As[wm * 32 + m * 16 + (lane & 15)][ks * 32 + (lane >> 4) * 8]);
#pragma unroll
      for (int n = 0; n < 2; ++n)
        bg[n] = *reinterpret_cast<const bf16x8*>(
            &Bs[wn * 32 + n * 16 + (lane & 15)][ks * 32 + (lane >> 4) * 8]);
#pragma unroll
      for (int m = 0; m < 2; ++m)
#pragma unroll
        for (int n = 0; n < 2; ++n)
          acc[m][n] = __builtin_amdgcn_mfma_f32_16x16x32_bf16(af[m], bg[n], acc[m][n], 0, 0, 0);
    }
    __syncthreads();
  }

  const int rbase = row0 + wm * 32;
  const int cbase = col0 + wn * 32;
#pragma unroll
  for (int m = 0; m < 2; ++m)
#pragma unroll
    for (int n = 0; n < 2; ++n)
#pragma unroll
      for (int g = 0; g < 4; ++g) {
        int r = rbase + m * 16 + (lane >> 4) * 4 + g;
        if (r < nrows) {
          int c = cbase + n * 16 + (lane & 15);
          float x = fmaxf(acc[m][n][g], 0.f);
          if (MODE == 0) outb[(size_t)r * DOUT + c] = f32_bf16(x);
          else outf[(size_t)r * DOUT + c] = x;
        }
      }
}

// ---- L4: agg2 first (blocks 0..1023, the longer half), gemm1 after --------

__global__ __launch_bounds__(256, 4) void gemm1_agg2_kernel(const float* __restrict__ nf,
                                                            const int* __restrict__ selfrow1,
                                                            const unsigned short* __restrict__ agg1,
                                                            const unsigned short* __restrict__ Wb1,
                                                            unsigned short* __restrict__ h1c,
                                                            const int* __restrict__ nn_dev,
                                                            const int* __restrict__ cnt2,
                                                            const int2* __restrict__ bkt2,
                                                            const float* __restrict__ ef2,
                                                            unsigned short* __restrict__ agg2,
                                                            const float* __restrict__ zrow) {
  int b = blockIdx.x;
  if (b < AGG2_BLOCKS) {
    int wv = (b * 256 + threadIdx.x) >> 6;   // 0..4095
    int l = threadIdx.x & 63;
    int s0 = wv * 2;                          // 0..8190
    agg_two_segments(s0, true, s0 + 1, true, s0, cnt2, bkt2, ef2, agg2,
                     nf, zrow, l);
  } else {
    int g = b - AGG2_BLOCKS;                  // 0..511, col-fast
    gemm_body<0>(g >> 2, g & 3, nf, nullptr, selfrow1, nullptr, agg1, Wb1,
                 nullptr, h1c, *nn_dev);
  }
}

// ---- gemm2: col-fast grid (dim3(4,128)) so A-sharing blocks are adjacent --

__global__ __launch_bounds__(256, 4) void gemm2_kernel(const unsigned short* __restrict__ h1c,
                                                       const int* __restrict__ self2,
                                                       const int* __restrict__ remap,
                                                       const unsigned short* __restrict__ agg2,
                                                       const unsigned short* __restrict__ Wb2,
                                                       float* __restrict__ out) {
  gemm_body<1>(blockIdx.y, blockIdx.x, nullptr, h1c, self2, remap, agg2, Wb2,
               out, nullptr, BSZ);
}

// ---- launcher ------------------------------------------------------------

extern "C" void kernel_launch(void* const* d_in, const int* in_sizes, int n_in,
                              void* d_out, int out_size, void* d_ws, size_t ws_size,
                              hipStream_t stream) {
  const float* nf   = (const float*)d_in[0];
  const float* ef1  = (const float*)d_in[1];
  const float* ef2  = (const float*)d_in[2];
  const float* W1   = (const float*)d_in[3];
  const float* W2   = (const float*)d_in[4];
  const int* from1  = (const int*)d_in[5];
  const int* seg1   = (const int*)d_in[6];
  const int* self1  = (const int*)d_in[7];
  const int* from2  = (const int*)d_in[8];
  const int* seg2   = (const int*)d_in[9];
  const int* self2  = (const int*)d_in[10];
  float* out = (float*)d_out;

  char* w = (char*)d_ws;
  size_t o = 0;
  auto take = [&](size_t nb) -> char* {
    char* p = w + o;
    o += (nb + 255) & ~(size_t)255;
    return p;
  };
  // zero region (cleared by setup1): cnt1, cnt2, claim, nn, zrow — ZERO_INTS ints
  int* cnt1 = (int*)take((size_t)M1 * 4);
  int* cnt2 = (int*)take((size_t)BSZ * 4);
  int* claim = (int*)take((size_t)M1 * 4);
  int* nn   = (int*)take(256);
  float* zrow = (float*)take((size_t)256 * 4);
  int* remap    = (int*)take((size_t)M1 * 4);
  int* needed   = (int*)take((size_t)8192 * 4);
  int* selfrow1 = (int*)take((size_t)8192 * 4);
  int2* bkt1    = (int2*)take((size_t)M1 * 64 * 8);
  int2* bkt2    = (int2*)take((size_t)BSZ * 64 * 8);
  unsigned short* Wb1   = (unsigned short*)take((size_t)WELEMS * 2);
  unsigned short* Wb2   = (unsigned short*)take((size_t)WELEMS * 2);
  unsigned short* agg1c = (unsigned short*)take((size_t)8192 * DAGG * 2);
  unsigned short* agg2  = (unsigned short*)take((size_t)8192 * DAGG * 2);
  unsigned short* h1c   = (unsigned short*)take((size_t)8192 * DOUT * 2);

  setup1_kernel<<<S1_ZB, 1024, 0, stream>>>((int*)d_ws);
  setup2_kernel<<<S2_MB + S2_EB + S2_WB, 1024, 0, stream>>>(self2, claim, self1, remap,
                                                            needed, selfrow1, nn,
                                                            seg1, from1, cnt1, bkt1,
                                                            seg2, from2, cnt2, bkt2,
                                                            W1, W2, Wb1, Wb2);
  agg1_kernel<<<1024, 256, 0, stream>>>(needed, nn, cnt1, bkt1, ef1, agg1c, nf, zrow);
  gemm1_agg2_kernel<<<AGG2_BLOCKS + GEMM1_BLOCKS, 256, 0, stream>>>(nf, selfrow1, agg1c,
                                                                    Wb1, h1c, nn,
                                                                    cnt2, bkt2, ef2,
                                                                    agg2, zrow);
  gemm2_kernel<<<dim3(4, 128), 256, 0, stream>>>(h1c, self2, remap, agg2, Wb2, out);
}

// Round 16
// 89.647 us; speedup vs baseline: 1.1433x; 1.0658x over previous
//
#include <hip/hip_runtime.h>
#include <hip/hip_bf16.h>

#define N_NODES 100000
#define DN      256
#define DE      128
#define DOUT    256
#define M1      32768
#define BSZ     8192
#define E1      327680
#define E2      81920
#define DIN     640
#define DAGG    384
#define WELEMS  (DOUT * DIN)

#define CDIV(a,b) (((a)+(b)-1)/(b))

// zero region: cnt1[M1] cnt2[BSZ] claim[M1] nn[64] zrow[256] — contiguous ints at ws base
#define ZERO_INTS (M1 + BSZ + M1 + 64 + 256)
#define S1_ZB 73            // CDIV(ZERO_INTS, 1024)
#define S2_MB 8             // BSZ / 1024 (dedup blocks)
#define S2_E1B 320          // E1 / 1024 (E1 edge blocks)
// L3 (agg1mix, 256-thread blocks): E2 buckets, W convs, then agg1
#define L3_E2B 320          // E2 / 256
#define L3_WB  320          // 2*WELEMS / 4 / 256
#define L3_AGG 1024         // 4096 waves, 2 segs/wave
#define GEMM1_BLOCKS 512    // 128 row-tiles x 4 col-tiles

typedef __attribute__((ext_vector_type(8))) short bf16x8;
typedef __attribute__((ext_vector_type(4))) float f32x4;
typedef __attribute__((ext_vector_type(2))) float f32x2;
typedef __attribute__((ext_vector_type(4))) unsigned short u16x4;
typedef __attribute__((ext_vector_type(2))) unsigned short u16x2;

__device__ __forceinline__ unsigned short f32_bf16(float f) {
  unsigned u = __float_as_uint(f);
  unsigned r = (u + 0x7FFF + ((u >> 16) & 1)) >> 16;
  return (unsigned short)r;
}

// ---- setup1: zero bookkeeping region (tiny) --------------------------------

__global__ __launch_bounds__(1024) void setup1_kernel(int* __restrict__ zbase) {
  int i = blockIdx.x * 1024 + threadIdx.x;
  if (i < ZERO_INTS) zbase[i] = 0;
}

// ---- setup2a: CAS-dedup + E1 bucket CSR build (agg1's critical inputs) ----

__global__ __launch_bounds__(1024) void setup2a_kernel(const int* __restrict__ self2,
                                                       int* __restrict__ claim,
                                                       const int* __restrict__ self1,
                                                       int* __restrict__ remap,
                                                       int* __restrict__ needed,
                                                       int* __restrict__ selfrow1,
                                                       int* __restrict__ nn,
                                                       const int* __restrict__ seg1,
                                                       const int* __restrict__ from1,
                                                       int* __restrict__ cnt1,
                                                       int2* __restrict__ bkt1) {
  int b = blockIdx.x, t = threadIdx.x;
  if (b < S2_MB) {
    int m = self2[b * 1024 + t];
    if (atomicCAS(&claim[m], 0, 1) == 0) {
      int p = atomicAdd(nn, 1);
      remap[m] = p;
      needed[p] = m;
      selfrow1[p] = self1[m];
    }
  } else {
    int e = (b - S2_MB) * 1024 + t;
    int s = seg1[e];
    int p = atomicAdd(&cnt1[s], 1);
    if (p < 64) bkt1[s * 64 + p] = make_int2(from1[e], e);
  }
}

// ---- shared device body: aggregate 2 segments for one wave ----------------
// Lane l owns nf cols [4l..4l+3] (f32x4) and ef cols [2l..2l+1] (f32x2).

__device__ __forceinline__ void agg_two_segments(int m0, bool v0, int m1, bool v1,
                                                 int r0, const int* __restrict__ cnt,
                                                 const int2* __restrict__ bkt,
                                                 const float* __restrict__ ef,
                                                 unsigned short* __restrict__ aggout,
                                                 const float* __restrict__ nf,
                                                 const float* __restrict__ zrow,
                                                 int l) {
  int mm[2] = {m0, m1};
  bool vv[2] = {v0, v1};
  int base_[2], nc_[2];
#pragma unroll
  for (int s = 0; s < 2; ++s) {
    nc_[s] = vv[s] ? min(cnt[mm[s]], 64) : 0;
    base_[s] = mm[s] * 64;
  }
  int eidp[2], fidp[2];
#pragma unroll
  for (int s = 0; s < 2; ++s) {
    eidp[s] = 0; fidp[s] = 0;
    if (l < nc_[s]) {
      int2 d = bkt[base_[s] + l];
      fidp[s] = d.x; eidp[s] = d.y;
    }
  }
  const float* zra = zrow + l * 4;
  const float* zrb = zrow + l * 2;

  f32x4 accn[2];
  f32x2 accf[2];
#pragma unroll
  for (int s = 0; s < 2; ++s) {
    accn[s] = (f32x4)0.f;
    accf[s] = (f32x2)0.f;
    int nc = nc_[s];
    int eid = eidp[s], fid = fidp[s];
    for (int j = 0; j < nc; j += 8) {
      f32x4 a[8]; f32x2 b[8];
#pragma unroll
      for (int q = 0; q < 8; ++q) {
        int jj = j + q;
        int fq = __shfl(fid, jj & 63);
        int gq = __shfl(eid, jj & 63);
        bool ok = jj < nc;
        const float* pa = ok ? (nf + (size_t)fq * 256 + l * 4) : zra;
        const float* pb = ok ? (ef + (size_t)gq * 128 + l * 2) : zrb;
        a[q] = *reinterpret_cast<const f32x4*>(pa);
        b[q] = *reinterpret_cast<const f32x2*>(pb);
      }
      accn[s] += ((a[0] + a[1]) + (a[2] + a[3])) + ((a[4] + a[5]) + (a[6] + a[7]));
      accf[s] += ((b[0] + b[1]) + (b[2] + b[3])) + ((b[4] + b[5]) + (b[6] + b[7]));
    }
  }

#pragma unroll
  for (int s = 0; s < 2; ++s) {
    unsigned short* orow = aggout + (size_t)(r0 + s) * DAGG;
    u16x4 on;
    on[0] = f32_bf16(accn[s][0]); on[1] = f32_bf16(accn[s][1]);
    on[2] = f32_bf16(accn[s][2]); on[3] = f32_bf16(accn[s][3]);
    *reinterpret_cast<u16x4*>(orow + l * 4) = on;
    u16x2 oe;
    oe[0] = f32_bf16(accf[s][0]); oe[1] = f32_bf16(accf[s][1]);
    *reinterpret_cast<u16x2*>(orow + 256 + l * 2) = oe;
  }
}

// ---- L3: E2 buckets + W convs (backfill) then agg1 (critical path) --------
// E2/W work is needed only by L4, so it hides under agg1's gather stream.

__global__ __launch_bounds__(256) void agg1mix_kernel(const int* __restrict__ seg2,
                                                      const int* __restrict__ from2,
                                                      int* __restrict__ cnt2,
                                                      int2* __restrict__ bkt2,
                                                      const float* __restrict__ W1,
                                                      const float* __restrict__ W2,
                                                      unsigned short* __restrict__ Wb1,
                                                      unsigned short* __restrict__ Wb2,
                                                      const int* __restrict__ needed,
                                                      const int* __restrict__ nn_dev,
                                                      const int* __restrict__ cnt1,
                                                      const int2* __restrict__ bkt1,
                                                      const float* __restrict__ ef1,
                                                      unsigned short* __restrict__ agg1,
                                                      const float* __restrict__ nf,
                                                      const float* __restrict__ zrow) {
  int b = blockIdx.x, t = threadIdx.x;
  if (b < L3_E2B) {
    int e2 = b * 256 + t;
    int s = seg2[e2];
    int p = atomicAdd(&cnt2[s], 1);
    if (p < 64) bkt2[s * 64 + p] = make_int2(from2[e2], e2);
  } else if (b < L3_E2B + L3_WB) {
    int i = ((b - L3_E2B) * 256 + t) * 4;
    const float* s; unsigned short* d; int o;
    if (i < WELEMS) { s = W1; d = Wb1; o = i; }
    else { s = W2; d = Wb2; o = i - WELEMS; }
    f32x4 v = *reinterpret_cast<const f32x4*>(s + o);
    u16x4 r;
    r[0] = f32_bf16(v[0]); r[1] = f32_bf16(v[1]);
    r[2] = f32_bf16(v[2]); r[3] = f32_bf16(v[3]);
    *reinterpret_cast<u16x4*>(d + o) = r;
  } else {
    int wv = ((b - L3_E2B - L3_WB) * 256 + t) >> 6;   // 0..4095
    int l = t & 63;
    int s0 = wv * 2;
    int nnv = *nn_dev;
    bool v0 = s0 < nnv, v1 = (s0 + 1) < nnv;
    if (!v0) return;
    int m0 = needed[s0];
    int m1 = v1 ? needed[s0 + 1] : 0;
    agg_two_segments(m0, v0, m1, v1, s0, cnt1, bkt1, ef1, agg1, nf, zrow, l);
  }
}

// ---- GEMM device body (R8 shape: BM=64, BN=64, BK=64, prefetch) -----------
// MODE 0 (layer1): table = nf (f32), row = i1[r];        out = bf16 h1
// MODE 1 (layer2): table = h1 (bf16), row = i2[i1[r]];   out = f32 final

template<int MODE>
__device__ __forceinline__ void gemm_body(int bx, int by,
                                          const float* __restrict__ tabf,
                                          const unsigned short* __restrict__ tabb,
                                          const int* __restrict__ i1,
                                          const int* __restrict__ i2,
                                          const unsigned short* __restrict__ agg,
                                          const unsigned short* __restrict__ Wb,
                                          float* __restrict__ outf,
                                          unsigned short* __restrict__ outb,
                                          int nrows) {
  const int row0 = bx * 64;
  if (row0 >= nrows) return;
  const int col0 = by * 64;

  __shared__ unsigned short As[64][72];
  __shared__ unsigned short Bs[64][72];

  const int t = threadIdx.x;
  const int lane = t & 63, wid = t >> 6;
  const int wm = wid >> 1, wn = wid & 1;

  const int srow = t >> 2;
  const int scol = (t & 3) * 16;
  const int grow = row0 + srow;
  int ga = -1;
  if (grow < nrows) { int x = i1[grow]; ga = (MODE == 1) ? i2[x] : x; }
  const unsigned short* wrow = Wb + (size_t)(col0 + srow) * DIN + scol;
  const float* tabrow_f = (MODE == 0 && ga >= 0) ? tabf + (size_t)ga * 256 : nullptr;
  const unsigned short* tabrow_b = (MODE == 1 && ga >= 0) ? tabb + (size_t)ga * 256 : nullptr;
  const unsigned short* aggrow = agg + (size_t)grow * DAGG;

  f32x4 acc[2][2];
#pragma unroll
  for (int m = 0; m < 2; ++m)
#pragma unroll
    for (int n = 0; n < 2; ++n) acc[m][n] = (f32x4)0.f;

  bf16x8 ra0, ra1, rb0, rb1;

  auto loadA = [&](int k0, bf16x8& r0, bf16x8& r1) {
    int k = k0 + scol;
    if (ga < 0) { r0 = (bf16x8)(short)0; r1 = (bf16x8)(short)0; return; }
    if (k < 256) {
      if (MODE == 0) {
        const float* s = tabrow_f + k;
        f32x4 x0 = *reinterpret_cast<const f32x4*>(s);
        f32x4 x1 = *reinterpret_cast<const f32x4*>(s + 4);
        f32x4 x2 = *reinterpret_cast<const f32x4*>(s + 8);
        f32x4 x3 = *reinterpret_cast<const f32x4*>(s + 12);
#pragma unroll
        for (int j = 0; j < 4; ++j) {
          r0[j] = (short)f32_bf16(x0[j]); r0[4 + j] = (short)f32_bf16(x1[j]);
          r1[j] = (short)f32_bf16(x2[j]); r1[4 + j] = (short)f32_bf16(x3[j]);
        }
      } else {
        r0 = *reinterpret_cast<const bf16x8*>(tabrow_b + k);
        r1 = *reinterpret_cast<const bf16x8*>(tabrow_b + k + 8);
      }
    } else {
      r0 = *reinterpret_cast<const bf16x8*>(aggrow + (k - 256));
      r1 = *reinterpret_cast<const bf16x8*>(aggrow + (k - 256) + 8);
    }
  };

  loadA(0, ra0, ra1);
  rb0 = *reinterpret_cast<const bf16x8*>(wrow);
  rb1 = *reinterpret_cast<const bf16x8*>(wrow + 8);

  for (int k0 = 0; k0 < DIN; k0 += 64) {
    *reinterpret_cast<bf16x8*>(&As[srow][scol]) = ra0;
    *reinterpret_cast<bf16x8*>(&As[srow][scol + 8]) = ra1;
    *reinterpret_cast<bf16x8*>(&Bs[srow][scol]) = rb0;
    *reinterpret_cast<bf16x8*>(&Bs[srow][scol + 8]) = rb1;
    __syncthreads();

    if (k0 + 64 < DIN) {
      loadA(k0 + 64, ra0, ra1);
      rb0 = *reinterpret_cast<const bf16x8*>(wrow + k0 + 64);
      rb1 = *reinterpret_cast<const bf16x8*>(wrow + k0 + 64 + 8);
    }

#pragma unroll
    for (int ks = 0; ks < 2; ++ks) {
      bf16x8 af[2], bg[2];
#pragma unroll
      for (int m = 0; m < 2; ++m)
        af[m] = *reinterpret_cast<const bf16x8*>(
            &As[wm * 32 + m * 16 + (lane & 15)][ks * 32 + (lane >> 4) * 8]);
#pragma unroll
      for (int n = 0; n < 2; ++n)
        bg[n] = *reinterpret_cast<const bf16x8*>(
            &Bs[wn * 32 + n * 16 + (lane & 15)][ks * 32 + (lane >> 4) * 8]);
#pragma unroll
      for (int m = 0; m < 2; ++m)
#pragma unroll
        for (int n = 0; n < 2; ++n)
          acc[m][n] = __builtin_amdgcn_mfma_f32_16x16x32_bf16(af[m], bg[n], acc[m][n], 0, 0, 0);
    }
    __syncthreads();
  }

  const int rbase = row0 + wm * 32;
  const int cbase = col0 + wn * 32;
#pragma unroll
  for (int m = 0; m < 2; ++m)
#pragma unroll
    for (int n = 0; n < 2; ++n)
#pragma unroll
      for (int g = 0; g < 4; ++g) {
        int r = rbase + m * 16 + (lane >> 4) * 4 + g;
        if (r < nrows) {
          int c = cbase + n * 16 + (lane & 15);
          float x = fmaxf(acc[m][n][g], 0.f);
          if (MODE == 0) outb[(size_t)r * DOUT + c] = f32_bf16(x);
          else outf[(size_t)r * DOUT + c] = x;
        }
      }
}

// ---- L4: gemm1 (blocks 0..511) || agg2 (blocks 512..1535) — exact R12 -----

__global__ __launch_bounds__(256, 4) void gemm1_agg2_kernel(const float* __restrict__ nf,
                                                            const int* __restrict__ selfrow1,
                                                            const unsigned short* __restrict__ agg1,
                                                            const unsigned short* __restrict__ Wb1,
                                                            unsigned short* __restrict__ h1c,
                                                            const int* __restrict__ nn_dev,
                                                            const int* __restrict__ cnt2,
                                                            const int2* __restrict__ bkt2,
                                                            const float* __restrict__ ef2,
                                                            unsigned short* __restrict__ agg2,
                                                            const float* __restrict__ zrow) {
  int b = blockIdx.x;
  if (b < GEMM1_BLOCKS) {
    gemm_body<0>(b >> 2, b & 3, nf, nullptr, selfrow1, nullptr, agg1, Wb1,
                 nullptr, h1c, *nn_dev);
  } else {
    int wv = ((b - GEMM1_BLOCKS) * 256 + threadIdx.x) >> 6;  // 0..4095
    int l = threadIdx.x & 63;
    int s0 = wv * 2;                                          // 0..8190
    agg_two_segments(s0, true, s0 + 1, true, s0, cnt2, bkt2, ef2, agg2,
                     nf, zrow, l);
  }
}

// ---- gemm2 — exact R12 -----------------------------------------------------

__global__ __launch_bounds__(256, 4) void gemm2_kernel(const unsigned short* __restrict__ h1c,
                                                       const int* __restrict__ self2,
                                                       const int* __restrict__ remap,
                                                       const unsigned short* __restrict__ agg2,
                                                       const unsigned short* __restrict__ Wb2,
                                                       float* __restrict__ out) {
  gemm_body<1>(blockIdx.x, blockIdx.y, nullptr, h1c, self2, remap, agg2, Wb2,
               out, nullptr, BSZ);
}

// ---- launcher ------------------------------------------------------------

extern "C" void kernel_launch(void* const* d_in, const int* in_sizes, int n_in,
                              void* d_out, int out_size, void* d_ws, size_t ws_size,
                              hipStream_t stream) {
  const float* nf   = (const float*)d_in[0];
  const float* ef1  = (const float*)d_in[1];
  const float* ef2  = (const float*)d_in[2];
  const float* W1   = (const float*)d_in[3];
  const float* W2   = (const float*)d_in[4];
  const int* from1  = (const int*)d_in[5];
  const int* seg1   = (const int*)d_in[6];
  const int* self1  = (const int*)d_in[7];
  const int* from2  = (const int*)d_in[8];
  const int* seg2   = (const int*)d_in[9];
  const int* self2  = (const int*)d_in[10];
  float* out = (float*)d_out;

  char* w = (char*)d_ws;
  size_t o = 0;
  auto take = [&](size_t nb) -> char* {
    char* p = w + o;
    o += (nb + 255) & ~(size_t)255;
    return p;
  };
  // zero region (cleared by setup1): cnt1, cnt2, claim, nn, zrow — ZERO_INTS ints
  int* cnt1 = (int*)take((size_t)M1 * 4);
  int* cnt2 = (int*)take((size_t)BSZ * 4);
  int* claim = (int*)take((size_t)M1 * 4);
  int* nn   = (int*)take(256);
  float* zrow = (float*)take((size_t)256 * 4);
  int* remap    = (int*)take((size_t)M1 * 4);
  int* needed   = (int*)take((size_t)8192 * 4);
  int* selfrow1 = (int*)take((size_t)8192 * 4);
  int2* bkt1    = (int2*)take((size_t)M1 * 64 * 8);
  int2* bkt2    = (int2*)take((size_t)BSZ * 64 * 8);
  unsigned short* Wb1   = (unsigned short*)take((size_t)WELEMS * 2);
  unsigned short* Wb2   = (unsigned short*)take((size_t)WELEMS * 2);
  unsigned short* agg1c = (unsigned short*)take((size_t)8192 * DAGG * 2);
  unsigned short* agg2  = (unsigned short*)take((size_t)8192 * DAGG * 2);
  unsigned short* h1c   = (unsigned short*)take((size_t)8192 * DOUT * 2);

  setup1_kernel<<<S1_ZB, 1024, 0, stream>>>((int*)d_ws);
  setup2a_kernel<<<S2_MB + S2_E1B, 1024, 0, stream>>>(self2, claim, self1, remap, needed,
                                                      selfrow1, nn,
                                                      seg1, from1, cnt1, bkt1);
  agg1mix_kernel<<<L3_E2B + L3_WB + L3_AGG, 256, 0, stream>>>(seg2, from2, cnt2, bkt2,
                                                              W1, W2, Wb1, Wb2,
                                                              needed, nn, cnt1, bkt1,
                                                              ef1, agg1c, nf, zrow);
  gemm1_agg2_kernel<<<GEMM1_BLOCKS + 1024, 256, 0, stream>>>(nf, selfrow1, agg1c, Wb1,
                                                             h1c, nn,
                                                             cnt2, bkt2, ef2, agg2, zrow);
  gemm2_kernel<<<dim3(128, 4), 256, 0, stream>>>(h1c, self2, remap, agg2, Wb2, out);
}